// Round 1
// baseline (43.141 us; speedup 1.0000x reference)
//
#include <hip/hip_runtime.h>

// Batched histogram with position cutoff:
// token_count[b, v] = #{ s : s < last_token_index[b] and input_ids[b, s] == v }
// B=256, S=4096, V=128000. Output int32 (B*V = 32,768,000 elements, 131 MB).
//
// Cost model: zero-fill of 131 MB output dominates (HBM-write-bound).
// Scatter is ~0.5M random atomics -> small.

#define THREADS 256
#define CHUNKS_PER_ROW 4   // S=4096 -> each block handles 1024 positions

__global__ __launch_bounds__(THREADS) void hist_kernel(
    const int* __restrict__ input_ids,        // (B, S)
    const int* __restrict__ last_token_index, // (B, 1)
    int* __restrict__ out,                    // (B, V)
    int S, int V)
{
    const int b     = blockIdx.x / CHUNKS_PER_ROW;
    const int chunk = blockIdx.x % CHUNKS_PER_ROW;
    const int chunk_len = S / CHUNKS_PER_ROW;

    const int L = last_token_index[b];        // valid positions: s < L
    const int s_begin = chunk * chunk_len;
    if (s_begin >= L) return;                 // whole chunk invalid
    const int s_end = min(s_begin + chunk_len, L);

    const int* row = input_ids + (size_t)b * S;
    int* out_row   = out + (size_t)b * V;

    for (int s = s_begin + threadIdx.x; s < s_end; s += THREADS) {
        int v = row[s];
        atomicAdd(&out_row[v], 1);
    }
}

extern "C" void kernel_launch(void* const* d_in, const int* in_sizes, int n_in,
                              void* d_out, int out_size, void* d_ws, size_t ws_size,
                              hipStream_t stream) {
    const int* input_ids        = (const int*)d_in[0];
    const int* last_token_index = (const int*)d_in[1];
    // d_in[2] is vocab_size scalar (128000), known statically but read for safety
    const int V = 128000;
    const int B = 256;
    const int S = in_sizes[0] / B;            // 4096

    int* out = (int*)d_out;

    // Zero the output (must do every call: harness poisons once, never re-poisons).
    hipMemsetAsync(out, 0, (size_t)out_size * sizeof(int), stream);

    // Scatter-add histogram.
    dim3 grid(B * CHUNKS_PER_ROW);
    hist_kernel<<<grid, THREADS, 0, stream>>>(input_ids, last_token_index, out, S, V);
}

// Round 2
// 39.400 us; speedup vs baseline: 1.0949x; 1.0949x over previous
//
#include <hip/hip_runtime.h>

// Batched histogram with position cutoff:
// token_count[b, v] = #{ s : s < last_token_index[b] and input_ids[b, s] == v }
// B=256, S=4096, V=128000. Output int32 (B*V = 32,768,000 elements, 131 MB).
//
// Fused design: one block per batch row. The block
//   1) zero-fills its own 512 KB output row (int4 stores, coalesced),
//   2) __syncthreads()  -> vmcnt(0) drain, zeros visible at L2,
//   3) scatters <=4096 atomicAdds into the just-zeroed row (L2-warm).
// This removes the separate memset launch + serialization and overlaps
// zero-writes with atomic RMW across blocks. HBM floor ~135 MB ~ 20.5 us.

#define NB   256
#define SLEN 4096
#define VOC  128000
#define THREADS 1024

__global__ __launch_bounds__(THREADS) void fused_hist_kernel(
    const int* __restrict__ input_ids,        // (B, S)
    const int* __restrict__ last_token_index, // (B, 1)
    int* __restrict__ out)                    // (B, V)
{
    const int b = blockIdx.x;

    int* __restrict__ row_out = out + (size_t)b * VOC;
    const int* __restrict__ row_in = input_ids + (size_t)b * SLEN;

    // Read cutoff early (independent scalar-ish load).
    const int L = last_token_index[b];

    // ---- Phase 1: zero the row. VOC = 128000 ints = 32000 int4. ----
    int4 z; z.x = 0; z.y = 0; z.z = 0; z.w = 0;
    int4* __restrict__ p4 = reinterpret_cast<int4*>(row_out);
    const int n4 = VOC / 4; // 32000
    for (int i = threadIdx.x; i < n4; i += THREADS) {
        p4[i] = z;
    }

    // Ensure all zero-stores are globally visible (same-block ordering:
    // __syncthreads implies s_waitcnt vmcnt(0) before the barrier).
    __syncthreads();

    // ---- Phase 2: scatter-add. Only this block touches this row. ----
    for (int s = threadIdx.x; s < L; s += THREADS) {
        int v = row_in[s];
        atomicAdd(&row_out[v], 1);
    }
}

extern "C" void kernel_launch(void* const* d_in, const int* in_sizes, int n_in,
                              void* d_out, int out_size, void* d_ws, size_t ws_size,
                              hipStream_t stream) {
    const int* input_ids        = (const int*)d_in[0];
    const int* last_token_index = (const int*)d_in[1];
    int* out = (int*)d_out;

    fused_hist_kernel<<<dim3(NB), dim3(THREADS), 0, stream>>>(
        input_ids, last_token_index, out);
}

// Round 3
// 25.237 us; speedup vs baseline: 1.7095x; 1.5612x over previous
//
#include <hip/hip_runtime.h>

// Batched histogram with position cutoff:
// token_count[b, v] = #{ s : s < last_token_index[b] and input_ids[b, s] == v }
// B=256, S=4096, V=128000. Output int32 (131 MB).
//
// Design: LDS-privatized histogram, no global atomics.
//   grid = B * 2 blocks; block (b, half) owns vocab range [half*64000, +64000).
//   1024 threads, 64 KB LDS (16000 int bins) -> 2 blocks/CU, 32 waves/CU.
//   Each block: load row tokens once into registers (4/thread), then 4 passes:
//     zero LDS -> LDS atomicAdd for in-range tokens -> int4-stream LDS to out.
//   The LDS zero doubles as the output zero-fill, so global traffic is pure
//   streaming: 131 MB stores + ~8 MB loads. Floor ~21 us at 6.6 TB/s.

#define NB      256
#define SLEN    4096
#define VOC     128000
#define THREADS 1024
#define HALF_BINS   64000   // bins per block
#define PASS_BINS   16000   // bins per pass (64 KB LDS)
#define NPASS       4       // HALF_BINS / PASS_BINS
#define TOK_PER_THR 4       // SLEN / THREADS

__global__ __launch_bounds__(THREADS) void fused_hist_kernel(
    const int* __restrict__ input_ids,        // (B, S)
    const int* __restrict__ last_token_index, // (B, 1)
    int* __restrict__ out)                    // (B, V)
{
    __shared__ int lds[PASS_BINS];            // 64 KB

    const int half = blockIdx.x & 1;
    const int b    = blockIdx.x >> 1;

    const int* __restrict__ row_in = input_ids + (size_t)b * SLEN;
    int* __restrict__ row_out      = out + (size_t)b * VOC + half * HALF_BINS;

    const int L = last_token_index[b];        // valid: s < L

    // Load this row's tokens once; invalid positions get a sentinel
    // that is out of range for every pass.
    int v[TOK_PER_THR];
#pragma unroll
    for (int k = 0; k < TOK_PER_THR; ++k) {
        const int s = threadIdx.x + k * THREADS;
        const int t = row_in[s];
        v[k] = (s < L) ? t : 0x40000000;
    }

    const int base = half * HALF_BINS;
    int4 z; z.x = 0; z.y = 0; z.z = 0; z.w = 0;

    for (int p = 0; p < NPASS; ++p) {
        const int lo = base + p * PASS_BINS;

        // ---- zero the LDS segment (4000 int4) ----
        int4* __restrict__ l4 = reinterpret_cast<int4*>(lds);
        for (int i = threadIdx.x; i < PASS_BINS / 4; i += THREADS) {
            l4[i] = z;
        }
        __syncthreads();

        // ---- LDS scatter for tokens in [lo, lo+PASS_BINS) ----
#pragma unroll
        for (int k = 0; k < TOK_PER_THR; ++k) {
            const unsigned d = (unsigned)(v[k] - lo);
            if (d < (unsigned)PASS_BINS) {
                atomicAdd(&lds[d], 1);
            }
        }
        __syncthreads();

        // ---- stream the finished segment to global (coalesced int4) ----
        const int4* __restrict__ s4 = reinterpret_cast<const int4*>(lds);
        int4* __restrict__ d4 = reinterpret_cast<int4*>(row_out + p * PASS_BINS);
        for (int i = threadIdx.x; i < PASS_BINS / 4; i += THREADS) {
            d4[i] = s4[i];
        }

        // Reads of lds must finish before next pass re-zeroes it.
        if (p + 1 < NPASS) __syncthreads();
    }
}

extern "C" void kernel_launch(void* const* d_in, const int* in_sizes, int n_in,
                              void* d_out, int out_size, void* d_ws, size_t ws_size,
                              hipStream_t stream) {
    const int* input_ids        = (const int*)d_in[0];
    const int* last_token_index = (const int*)d_in[1];
    int* out = (int*)d_out;

    fused_hist_kernel<<<dim3(NB * 2), dim3(THREADS), 0, stream>>>(
        input_ids, last_token_index, out);
}

// Round 4
// 24.221 us; speedup vs baseline: 1.7812x; 1.0420x over previous
//
#include <hip/hip_runtime.h>

// Batched histogram with position cutoff:
// token_count[b, v] = #{ s : s < last_token_index[b] and input_ids[b, s] == v }
// B=256, S=4096, V=128000. Output int32 (131 MB).
//
// Design (R4): 16-bit packed LDS bins, single pass, no global atomics.
//   Counts are bounded by S=4096 < 2^16, so 16-bit bins are exact.
//   grid = B*4 blocks; block (b, part) owns bins [part*32000, +32000)
//   = 64 KB LDS packed 2 bins/word. 1024 threads -> 2 blocks/CU resident,
//   so one block's global-store phase overlaps the other's zero/scatter.
//   Phases: zero LDS -> sync -> packed LDS atomics -> sync -> expand+store.
//   16-bit emulated atomic: atomicAdd(&lds[d>>1], 1 << ((d&1)*16));
//   low half can never carry into high half (max count 4096).
//   Global traffic: 131 MB streaming stores + <=16 MB reads. Floor ~20 us.

#define NB      256
#define SLEN    4096
#define VOC     128000
#define THREADS 1024
#define BLOCKS_PER_ROW 4
#define BINS    32000          // bins per block
#define WORDS   (BINS / 2)     // 16000 packed 32-bit words = 64 KB

__global__ __launch_bounds__(THREADS) void fused_hist_kernel(
    const int* __restrict__ input_ids,        // (B, S)
    const int* __restrict__ last_token_index, // (B, 1)
    int* __restrict__ out)                    // (B, V)
{
    __shared__ int lds[WORDS];                // 64 KB

    const int part = blockIdx.x & (BLOCKS_PER_ROW - 1);
    const int b    = blockIdx.x / BLOCKS_PER_ROW;
    const int lo   = part * BINS;

    const int* __restrict__ row_in = input_ids + (size_t)b * SLEN;
    int* __restrict__ row_out      = out + (size_t)b * VOC + lo;

    const int L = last_token_index[b];        // valid: s < L

    // ---- Load this thread's 4 tokens (int4, coalesced); skip past cutoff ----
    const int s0 = threadIdx.x * 4;           // SLEN / THREADS == 4
    int4 t; t.x = t.y = t.z = t.w = 0x40000000;  // sentinel: out of every range
    if (s0 < L) {
        t = *reinterpret_cast<const int4*>(row_in + s0);
        // mask positions >= L
        if (s0 + 1 >= L) t.y = 0x40000000;
        if (s0 + 2 >= L) t.z = 0x40000000;
        if (s0 + 3 >= L) t.w = 0x40000000;
    }

    // ---- Phase 1: zero LDS (4000 int4) ----
    int4 z; z.x = 0; z.y = 0; z.z = 0; z.w = 0;
    int4* __restrict__ l4 = reinterpret_cast<int4*>(lds);
    for (int i = threadIdx.x; i < WORDS / 4; i += THREADS) {
        l4[i] = z;
    }
    __syncthreads();

    // ---- Phase 2: packed 16-bit scatter into this block's bin range ----
    {
        const int tok[4] = { t.x, t.y, t.z, t.w };
#pragma unroll
        for (int k = 0; k < 4; ++k) {
            const unsigned d = (unsigned)(tok[k] - lo);
            if (d < (unsigned)BINS) {
                atomicAdd(&lds[d >> 1], 1 << ((d & 1) * 16));
            }
        }
    }
    __syncthreads();

    // ---- Phase 3: expand packed counts and stream to global (int4) ----
    const int2* __restrict__ src = reinterpret_cast<const int2*>(lds); // 8000 int2
    int4* __restrict__ dst = reinterpret_cast<int4*>(row_out);         // 8000 int4
    for (int i = threadIdx.x; i < BINS / 4; i += THREADS) {
        int2 w = src[i];
        int4 o;
        o.x = w.x & 0xFFFF;
        o.y = (int)((unsigned)w.x >> 16);
        o.z = w.y & 0xFFFF;
        o.w = (int)((unsigned)w.y >> 16);
        dst[i] = o;
    }
}

extern "C" void kernel_launch(void* const* d_in, const int* in_sizes, int n_in,
                              void* d_out, int out_size, void* d_ws, size_t ws_size,
                              hipStream_t stream) {
    const int* input_ids        = (const int*)d_in[0];
    const int* last_token_index = (const int*)d_in[1];
    int* out = (int*)d_out;

    fused_hist_kernel<<<dim3(NB * BLOCKS_PER_ROW), dim3(THREADS), 0, stream>>>(
        input_ids, last_token_index, out);
}